// Round 5
// baseline (1224.831 us; speedup 1.0000x reference)
//
#include <hip/hip_runtime.h>

typedef _Float16 half8 __attribute__((ext_vector_type(8)));
typedef float f32x4 __attribute__((ext_vector_type(4)));

#define B_SZ   2048
#define T_SZ   128
#define IN_SZ  64
#define H_SZ   256
#define G4     1024          // 4*H
#define KTOT   320           // IN + H
#define KT_N   10            // K tiles of 32
#define M_BLK  8
#define NBLK   (B_SZ / M_BLK)   // 256 blocks -> 1 per CU
#define NTHR   512              // 8 waves
#define A_PAD  328              // LDS A row stride in halves
#define KT_REG 4                // kt 0..3 pinned in VGPRs (128 VGPR/wave)
#define KT_LDS 2                // kt 4..5 in LDS (128 KB/block)

__device__ __forceinline__ float sigmoidf_(float x) { return 1.0f / (1.0f + __expf(-x)); }
__device__ __forceinline__ float tanhf_(float x) { return 1.0f - 2.0f / (__expf(2.0f * x) + 1.0f); }

// Repack [W_ih | W_hh] -> fp16, gate-reordered, MFMA-fragment-ordered.
// rp = w*128 + q*32 + j  ->  original gate row g = q*256 + w*32 + j.
// Frag (nb,kt): flat [(nb*10+kt)*64 + lane]*8 halves; lane l holds row
// nb*16+(l&15), k = kt*32 + (l>>4)*8 .. +8.
__global__ void prep_kernel(const float* __restrict__ W_ih,
                            const float* __restrict__ W_hh,
                            const float* __restrict__ b_ih,
                            const float* __restrict__ b_hh,
                            _Float16* __restrict__ Wpp,
                            float* __restrict__ biasp) {
  const int tid = blockIdx.x * blockDim.x + threadIdx.x;
  if (tid < G4) {
    const int rp = tid;
    const int w = rp >> 7, q = (rp >> 5) & 3, j = rp & 31;
    const int g = q * 256 + w * 32 + j;
    biasp[rp] = b_ih[g] + b_hh[g];
  }
  const int l  = tid & 63;
  const int kt = (tid >> 6) % KT_N;
  const int nb = tid / (64 * KT_N);
  if (nb >= G4 / 16) return;
  const int rp = nb * 16 + (l & 15);
  const int w = rp >> 7, q = (rp >> 5) & 3, j = rp & 31;
  const int g = q * 256 + w * 32 + j;
  const int k0 = kt * 32 + (l >> 4) * 8;
  _Float16 v[8];
  #pragma unroll
  for (int kk = 0; kk < 8; ++kk) {
    const int k = k0 + kk;
    const float f = (k < IN_SZ) ? W_ih[g * IN_SZ + k]
                                : W_hh[g * H_SZ + (k - IN_SZ)];
    v[kk] = (_Float16)f;
  }
  *(half8*)(Wpp + ((size_t)(nb * KT_N + kt) * 64 + l) * 8) = *(half8*)v;
}

__global__ __attribute__((amdgpu_waves_per_eu(2, 2))) __launch_bounds__(NTHR)
void lstm_kernel(const float* __restrict__ x,
                 const _Float16* __restrict__ Wpp,
                 const float* __restrict__ biasp,
                 const float* __restrict__ fcW,
                 const float* __restrict__ fcb,
                 float* __restrict__ out) {
  __shared__ __align__(16) _Float16 Abuf[2][8][A_PAD];    // 10496 B
  __shared__ __align__(16) _Float16 Blds[128 * 512];      // 131072 B (kt4,5)
  __shared__ float bl[G4];                                // 4096 B
  __shared__ float red[M_BLK][16];                        // 512 B

  const int tid = threadIdx.x;
  const int l   = tid & 63;
  const int w   = tid >> 6;     // wave 0..7 -> owns h-cols [w*32, w*32+32)
  const int lm  = l & 15;
  const int lk  = l >> 4;
  const int r0  = blockIdx.x * M_BLK;

  // zero A buffers (h_{-1} = 0)
  {
    _Float16* ab = &Abuf[0][0][0];
    for (int i = tid; i < 2 * 8 * A_PAD; i += NTHR) ab[i] = (_Float16)0.0f;
  }

  const _Float16* wbase = Wpp + (size_t)w * 8 * KT_N * 512 + (size_t)l * 8;

  // VGPR-resident W: kt 0..3, pinned via asm value-barrier (remat-proof)
  half8 Wf[8][KT_REG];
  #pragma unroll
  for (int nt = 0; nt < 8; ++nt)
    #pragma unroll
    for (int kt = 0; kt < KT_REG; ++kt)
      Wf[nt][kt] = *(const half8*)(wbase + (size_t)(nt * KT_N + kt) * 512);
  #pragma unroll
  for (int nt = 0; nt < 8; ++nt)
    #pragma unroll
    for (int kt = 0; kt < KT_REG; ++kt)
      asm volatile("" : "+v"(Wf[nt][kt]));

  __syncthreads();  // zeroing visible before x0/h writes

  // stage x_0 into buf 0
  {
    const int r = tid >> 6, cc = tid & 63;
    Abuf[0][r][cc] = (_Float16)x[((size_t)(r0 + r) * T_SZ) * IN_SZ + cc];
  }
  // LDS-resident W: kt 4..5
  #pragma unroll
  for (int nt = 0; nt < 8; ++nt)
    #pragma unroll
    for (int j = 0; j < KT_LDS; ++j)
      *(half8*)&Blds[((w * 16 + nt * 2 + j) * 512) + l * 8] =
          *(const half8*)(wbase + (size_t)(nt * KT_N + KT_REG + j) * 512);
  // bias into LDS
  bl[tid] = biasp[tid];
  bl[tid + NTHR] = biasp[tid + NTHR];

  __syncthreads();

  float cst[2][4] = {};

  for (int t = 0; t < T_SZ; ++t) {
    const _Float16 (*Ain)[A_PAD] = Abuf[t & 1];
    _Float16 (*Aout)[A_PAD] = Abuf[(t + 1) & 1];

    // stream kt6,7: issue all 16 loads up front
    half8 st0[8], st1[8];
    #pragma unroll
    for (int nt = 0; nt < 8; ++nt)
      st0[nt] = *(const half8*)(wbase + (size_t)(nt * KT_N + 6) * 512);
    #pragma unroll
    for (int nt = 0; nt < 8; ++nt)
      st1[nt] = *(const half8*)(wbase + (size_t)(nt * KT_N + 7) * 512);

    // stage x_{t+1} (overlaps GEMM)
    if (t + 1 < T_SZ) {
      const int r = tid >> 6, cc = tid & 63;
      Aout[r][cc] = (_Float16)x[((size_t)(r0 + r) * T_SZ + (t + 1)) * IN_SZ + cc];
    }

    // init acc from bias (same value for all 4 rows of a tile)
    f32x4 acc[8];
    #pragma unroll
    for (int nt = 0; nt < 8; ++nt) {
      const float b = bl[w * 128 + nt * 16 + lm];
      acc[nt] = (f32x4){b, b, b, b};
    }

    #define LA(kt) (*(const half8*)&Ain[lm & 7][(kt) * 32 + lk * 8])
    half8 a_cur = LA(0), a_nx = LA(1);

    // kt 0..3: pinned VGPR W
    #pragma unroll
    for (int nt = 0; nt < 8; ++nt)
      acc[nt] = __builtin_amdgcn_mfma_f32_16x16x32_f16(a_cur, Wf[nt][0], acc[nt], 0, 0, 0);
    a_cur = a_nx; a_nx = LA(2);
    #pragma unroll
    for (int nt = 0; nt < 8; ++nt)
      acc[nt] = __builtin_amdgcn_mfma_f32_16x16x32_f16(a_cur, Wf[nt][1], acc[nt], 0, 0, 0);
    a_cur = a_nx; a_nx = LA(3);
    #pragma unroll
    for (int nt = 0; nt < 8; ++nt)
      acc[nt] = __builtin_amdgcn_mfma_f32_16x16x32_f16(a_cur, Wf[nt][2], acc[nt], 0, 0, 0);
    a_cur = a_nx; a_nx = LA(4);
    #pragma unroll
    for (int nt = 0; nt < 8; ++nt)
      acc[nt] = __builtin_amdgcn_mfma_f32_16x16x32_f16(a_cur, Wf[nt][3], acc[nt], 0, 0, 0);
    a_cur = a_nx; a_nx = LA(5);

    // kt 4..5: LDS-resident W
    #pragma unroll
    for (int nt = 0; nt < 8; ++nt) {
      const half8 bld = *(const half8*)&Blds[((w * 16 + nt * 2 + 0) * 512) + l * 8];
      acc[nt] = __builtin_amdgcn_mfma_f32_16x16x32_f16(a_cur, bld, acc[nt], 0, 0, 0);
    }
    a_cur = a_nx; a_nx = LA(6);
    #pragma unroll
    for (int nt = 0; nt < 8; ++nt) {
      const half8 bld = *(const half8*)&Blds[((w * 16 + nt * 2 + 1) * 512) + l * 8];
      acc[nt] = __builtin_amdgcn_mfma_f32_16x16x32_f16(a_cur, bld, acc[nt], 0, 0, 0);
    }
    a_cur = a_nx; a_nx = LA(7);

    // kt 6: consume st0, refill with kt8
    #pragma unroll
    for (int nt = 0; nt < 8; ++nt)
      acc[nt] = __builtin_amdgcn_mfma_f32_16x16x32_f16(a_cur, st0[nt], acc[nt], 0, 0, 0);
    #pragma unroll
    for (int nt = 0; nt < 8; ++nt)
      st0[nt] = *(const half8*)(wbase + (size_t)(nt * KT_N + 8) * 512);
    a_cur = a_nx; a_nx = LA(8);

    // kt 7: consume st1, refill with kt9
    #pragma unroll
    for (int nt = 0; nt < 8; ++nt)
      acc[nt] = __builtin_amdgcn_mfma_f32_16x16x32_f16(a_cur, st1[nt], acc[nt], 0, 0, 0);
    #pragma unroll
    for (int nt = 0; nt < 8; ++nt)
      st1[nt] = *(const half8*)(wbase + (size_t)(nt * KT_N + 9) * 512);
    a_cur = a_nx; a_nx = LA(9);

    // kt 8, 9
    #pragma unroll
    for (int nt = 0; nt < 8; ++nt)
      acc[nt] = __builtin_amdgcn_mfma_f32_16x16x32_f16(a_cur, st0[nt], acc[nt], 0, 0, 0);
    a_cur = a_nx;
    #pragma unroll
    for (int nt = 0; nt < 8; ++nt)
      acc[nt] = __builtin_amdgcn_mfma_f32_16x16x32_f16(a_cur, st1[nt], acc[nt], 0, 0, 0);
    #undef LA

    // cell update: tile nt = q*2 + jh; h-col = w*32 + jh*16 + lm; rows lk*4+r (lk<2)
    #pragma unroll
    for (int jh = 0; jh < 2; ++jh) {
      #pragma unroll
      for (int r = 0; r < 4; ++r) {
        const float iv = sigmoidf_(acc[0 + jh][r]);
        const float fv = sigmoidf_(acc[2 + jh][r]);
        const float gv = tanhf_   (acc[4 + jh][r]);
        const float ov = sigmoidf_(acc[6 + jh][r]);
        const float cn = fv * cst[jh][r] + iv * gv;
        cst[jh][r] = cn;
        const float hv = ov * tanhf_(cn);
        if (lk < 2) {
          const int m   = lk * 4 + r;
          const int col = w * 32 + jh * 16 + lm;
          Aout[m][IN_SZ + col] = (_Float16)hv;
        }
      }
    }
    __syncthreads();   // step-t Ain reads done AND Aout (x,h) visible
  }

  // out[r] = h_last[r,:] . fcW + fcb  (h_127 lives in Abuf[0] h-region)
  if (tid < 128) {
    const int r = tid >> 4, c0 = tid & 15;
    float p = 0.f;
    #pragma unroll
    for (int cc = 0; cc < 16; ++cc) {
      const int col = c0 + cc * 16;
      p += (float)Abuf[0][r][IN_SZ + col] * fcW[col];
    }
    red[r][c0] = p;
  }
  __syncthreads();
  if (tid < M_BLK) {
    float s = 0.f;
    #pragma unroll
    for (int k = 0; k < 16; ++k) s += red[tid][k];
    out[r0 + tid] = s + fcb[0];
  }
}

extern "C" void kernel_launch(void* const* d_in, const int* in_sizes, int n_in,
                              void* d_out, int out_size, void* d_ws, size_t ws_size,
                              hipStream_t stream) {
  const float* x    = (const float*)d_in[0];
  const float* W_ih = (const float*)d_in[1];
  const float* W_hh = (const float*)d_in[2];
  const float* b_ih = (const float*)d_in[3];
  const float* b_hh = (const float*)d_in[4];
  const float* fcW  = (const float*)d_in[5];
  const float* fcb  = (const float*)d_in[6];
  float* out = (float*)d_out;

  _Float16* Wpp = (_Float16*)d_ws;
  float* biasp  = (float*)((char*)d_ws + (size_t)G4 * KTOT * sizeof(_Float16));

  hipLaunchKernelGGL(prep_kernel, dim3(160), dim3(256), 0, stream,
                     W_ih, W_hh, b_ih, b_hh, Wpp, biasp);
  hipLaunchKernelGGL(lstm_kernel, dim3(NBLK), dim3(NTHR), 0, stream,
                     x, Wpp, biasp, fcW, fcb, out);
}

// Round 6
// 1137.713 us; speedup vs baseline: 1.0766x; 1.0766x over previous
//
#include <hip/hip_runtime.h>

typedef _Float16 half8 __attribute__((ext_vector_type(8)));
typedef float f32x4 __attribute__((ext_vector_type(4)));

#define B_SZ   2048
#define T_SZ   128
#define IN_SZ  64
#define H_SZ   256
#define G4     1024          // 4*H
#define KT_N   10            // K tiles of 32
#define M_BLK  16
#define NBLK   (B_SZ / M_BLK)   // 128 blocks (1 per CU, 128 CUs busy)
#define NTHR   1024             // 16 waves -> 4 waves/SIMD
#define A_PAD  328              // LDS A row stride in halves

__device__ __forceinline__ float sigmoidf_(float x) { return 1.0f / (1.0f + __expf(-x)); }
__device__ __forceinline__ float tanhf_(float x) { return 1.0f - 2.0f / (__expf(2.0f * x) + 1.0f); }

// Repack W -> fp16, fragment-ordered. Tile TI = w*4 + q (w = wave 0..15 owning
// h-cols [w*16,+16), q = gate). Tile row m -> orig gate row g = q*256 + w*16 + m.
// Frag: Wr[((TI*10+kt)*64 + l)*8]; lane l holds row m=l&15, k = kt*32+(l>>4)*8..+8.
__global__ void prep_kernel(const float* __restrict__ W_ih,
                            const float* __restrict__ W_hh,
                            const float* __restrict__ b_ih,
                            const float* __restrict__ b_hh,
                            _Float16* __restrict__ Wr,
                            float* __restrict__ biasp) {
  const int tid = blockIdx.x * blockDim.x + threadIdx.x;
  if (tid < G4) {
    const int TI = tid >> 4, m = tid & 15;
    const int w = TI >> 2, q = TI & 3;
    const int g = q * 256 + w * 16 + m;
    biasp[tid] = b_ih[g] + b_hh[g];
  }
  if (tid >= 64 * KT_N * 64) return;
  const int l  = tid & 63;
  const int kt = (tid >> 6) % KT_N;
  const int TI = tid / (64 * KT_N);
  const int lm = l & 15, lk = l >> 4;
  const int g  = (TI & 3) * 256 + (TI >> 2) * 16 + lm;
  const int k0 = kt * 32 + lk * 8;
  _Float16 v[8];
  #pragma unroll
  for (int kk = 0; kk < 8; ++kk) {
    const int k = k0 + kk;
    v[kk] = (_Float16)((k < IN_SZ) ? W_ih[g * IN_SZ + k] : W_hh[g * H_SZ + (k - IN_SZ)]);
  }
  *(half8*)&Wr[((size_t)(TI * KT_N + kt) * 64 + l) * 8] = *(half8*)v;
}

#define LDW(q, kt) (*(const half8*)&Wr[(((size_t)(w * 4 + (q)) * KT_N + (kt)) * 64 + l) * 8])

__global__ __launch_bounds__(NTHR)
void lstm_kernel(const float* __restrict__ x,
                 const _Float16* __restrict__ Wr,
                 const float* __restrict__ biasp,
                 const float* __restrict__ fcW,
                 const float* __restrict__ fcb,
                 float* __restrict__ out) {
  __shared__ __align__(16) _Float16 Abuf[2][M_BLK][A_PAD];  // 20992 B
  __shared__ __align__(16) _Float16 Blds[2 * 64 * 512];     // 131072 B (kt2,3)
  __shared__ float bl[G4];                                  // 4096 B
  __shared__ float red[M_BLK][16];                          // 1024 B

  const int tid = threadIdx.x;
  const int l   = tid & 63;
  const int w   = tid >> 6;      // wave 0..15 -> owns h-cols [w*16, w*16+16)
  const int lm  = l & 15;
  const int lk  = l >> 4;
  const int r0  = blockIdx.x * M_BLK;

  // zero A buffers (h_{-1} = 0)
  {
    _Float16* ab = &Abuf[0][0][0];
    for (int i = tid; i < 2 * M_BLK * A_PAD; i += NTHR) ab[i] = (_Float16)0.0f;
  }

  // VGPR-resident W: kt 0..1 for this wave's 4 gate-tiles
  half8 Wf[4][2];
  #pragma unroll
  for (int q = 0; q < 4; ++q)
    #pragma unroll
    for (int kt = 0; kt < 2; ++kt)
      Wf[q][kt] = LDW(q, kt);
  #pragma unroll
  for (int q = 0; q < 4; ++q)
    #pragma unroll
    for (int kt = 0; kt < 2; ++kt)
      asm volatile("" : "+v"(Wf[q][kt]));

  // LDS-resident W: kt 2..3 for all 64 tiles
  #pragma unroll
  for (int rep = 0; rep < 8; ++rep) {
    const int u  = rep * NTHR + tid;       // 0..8191 half8 copies
    const int TI = u >> 7;
    const int kt = (u >> 6) & 1;
    const int l2 = u & 63;
    *(half8*)&Blds[((size_t)(kt * 64 + TI) * 64 + l2) * 8] =
        *(const half8*)&Wr[((size_t)(TI * KT_N + 2 + kt) * 64 + l2) * 8];
  }

  bl[tid] = biasp[tid];

  // stage x_0 into buf 0
  {
    const int r = tid >> 6, cc = tid & 63;
    Abuf[0][r][cc] = (_Float16)x[((size_t)(r0 + r) * T_SZ) * IN_SZ + cc];
  }

  __syncthreads();

  // prologue: streams for kt4,5,6 in flight entering t=0
  half8 sA[4], sB[4], sC[4];
  #pragma unroll
  for (int q = 0; q < 4; ++q) sA[q] = LDW(q, 4);
  #pragma unroll
  for (int q = 0; q < 4; ++q) sB[q] = LDW(q, 5);
  #pragma unroll
  for (int q = 0; q < 4; ++q) sC[q] = LDW(q, 6);

  float cst[4] = {0.f, 0.f, 0.f, 0.f};

  for (int t = 0; t < T_SZ; ++t) {
    const _Float16 (*Ain)[A_PAD] = Abuf[t & 1];
    _Float16 (*Aout)[A_PAD] = Abuf[(t + 1) & 1];

    // x_{t+1}: issue load early, ds_write late
    float xv = 0.f;
    const bool hx = (t + 1 < T_SZ);
    if (hx) xv = x[((size_t)(r0 + (tid >> 6)) * T_SZ + (t + 1)) * IN_SZ + (tid & 63)];

    // acc init from bias
    f32x4 acc[4];
    #pragma unroll
    for (int q = 0; q < 4; ++q) {
      const float b = bl[(w * 4 + q) * 16 + lm];
      acc[q] = (f32x4){b, b, b, b};
    }

    #define LA(kt) (*(const half8*)&Ain[lm][(kt) * 32 + lk * 8])
    half8 a0 = LA(0), a1 = LA(1);

    // kt0,1: reg-resident W
    #pragma unroll
    for (int q = 0; q < 4; ++q)
      acc[q] = __builtin_amdgcn_mfma_f32_16x16x32_f16(a0, Wf[q][0], acc[q], 0, 0, 0);
    a0 = LA(2);
    #pragma unroll
    for (int q = 0; q < 4; ++q)
      acc[q] = __builtin_amdgcn_mfma_f32_16x16x32_f16(a1, Wf[q][1], acc[q], 0, 0, 0);
    a1 = LA(3);

    // kt2,3: LDS-resident W
    #pragma unroll
    for (int q = 0; q < 4; ++q) {
      const half8 bb = *(const half8*)&Blds[((size_t)(0 * 64 + w * 4 + q) * 64 + l) * 8];
      acc[q] = __builtin_amdgcn_mfma_f32_16x16x32_f16(a0, bb, acc[q], 0, 0, 0);
    }
    a0 = LA(4);
    #pragma unroll
    for (int q = 0; q < 4; ++q) {
      const half8 bb = *(const half8*)&Blds[((size_t)(1 * 64 + w * 4 + q) * 64 + l) * 8];
      acc[q] = __builtin_amdgcn_mfma_f32_16x16x32_f16(a1, bb, acc[q], 0, 0, 0);
    }
    a1 = LA(5);

    // kt4: consume sA, refill kt7
    #pragma unroll
    for (int q = 0; q < 4; ++q)
      acc[q] = __builtin_amdgcn_mfma_f32_16x16x32_f16(a0, sA[q], acc[q], 0, 0, 0);
    #pragma unroll
    for (int q = 0; q < 4; ++q) sA[q] = LDW(q, 7);
    a0 = LA(6);

    // kt5: consume sB, refill kt8
    #pragma unroll
    for (int q = 0; q < 4; ++q)
      acc[q] = __builtin_amdgcn_mfma_f32_16x16x32_f16(a1, sB[q], acc[q], 0, 0, 0);
    #pragma unroll
    for (int q = 0; q < 4; ++q) sB[q] = LDW(q, 8);
    a1 = LA(7);

    // kt6: consume sC, refill kt9
    #pragma unroll
    for (int q = 0; q < 4; ++q)
      acc[q] = __builtin_amdgcn_mfma_f32_16x16x32_f16(a0, sC[q], acc[q], 0, 0, 0);
    #pragma unroll
    for (int q = 0; q < 4; ++q) sC[q] = LDW(q, 9);
    a0 = LA(8);

    // kt7: consume sA, refill NEXT step's kt4 (cross-step prefetch)
    #pragma unroll
    for (int q = 0; q < 4; ++q)
      acc[q] = __builtin_amdgcn_mfma_f32_16x16x32_f16(a1, sA[q], acc[q], 0, 0, 0);
    #pragma unroll
    for (int q = 0; q < 4; ++q) sA[q] = LDW(q, 4);
    a1 = LA(9);

    // kt8: consume sB, refill next kt5
    #pragma unroll
    for (int q = 0; q < 4; ++q)
      acc[q] = __builtin_amdgcn_mfma_f32_16x16x32_f16(a0, sB[q], acc[q], 0, 0, 0);
    #pragma unroll
    for (int q = 0; q < 4; ++q) sB[q] = LDW(q, 5);

    // kt9: consume sC, refill next kt6
    #pragma unroll
    for (int q = 0; q < 4; ++q)
      acc[q] = __builtin_amdgcn_mfma_f32_16x16x32_f16(a1, sC[q], acc[q], 0, 0, 0);
    #pragma unroll
    for (int q = 0; q < 4; ++q) sC[q] = LDW(q, 6);
    #undef LA

    // cell update: lane (lm,lk): batch rows lk*4+r, h-col w*16+lm, gates = acc[q][r]
    #pragma unroll
    for (int r = 0; r < 4; ++r) {
      const float iv = sigmoidf_(acc[0][r]);
      const float fv = sigmoidf_(acc[1][r]);
      const float gv = tanhf_   (acc[2][r]);
      const float ov = sigmoidf_(acc[3][r]);
      const float cn = fv * cst[r] + iv * gv;
      cst[r] = cn;
      const float hv = ov * tanhf_(cn);
      Aout[lk * 4 + r][IN_SZ + w * 16 + lm] = (_Float16)hv;
    }
    if (hx) Aout[tid >> 6][tid & 63] = (_Float16)xv;

    // LDS-only fence + raw barrier: streamed W loads stay in flight (no vmcnt drain)
    asm volatile("s_waitcnt lgkmcnt(0)" ::: "memory");
    __builtin_amdgcn_s_barrier();
  }

  // out[r] = h_127[r,:] . fcW + fcb  (h_127 lives in Abuf[0] h-region)
  if (tid < 256) {
    const int r = tid >> 4, c0 = tid & 15;
    float p = 0.f;
    #pragma unroll
    for (int cc = 0; cc < 16; ++cc) {
      const int col = c0 + cc * 16;
      p += (float)Abuf[0][r][IN_SZ + col] * fcW[col];
    }
    red[r][c0] = p;
  }
  __syncthreads();
  if (tid < M_BLK) {
    float s = 0.f;
    #pragma unroll
    for (int k = 0; k < 16; ++k) s += red[tid][k];
    out[r0 + tid] = s + fcb[0];
  }
}

extern "C" void kernel_launch(void* const* d_in, const int* in_sizes, int n_in,
                              void* d_out, int out_size, void* d_ws, size_t ws_size,
                              hipStream_t stream) {
  const float* x    = (const float*)d_in[0];
  const float* W_ih = (const float*)d_in[1];
  const float* W_hh = (const float*)d_in[2];
  const float* b_ih = (const float*)d_in[3];
  const float* b_hh = (const float*)d_in[4];
  const float* fcW  = (const float*)d_in[5];
  const float* fcb  = (const float*)d_in[6];
  float* out = (float*)d_out;

  _Float16* Wr  = (_Float16*)d_ws;
  float* biasp  = (float*)((char*)d_ws + (size_t)G4 * 320 * sizeof(_Float16));

  hipLaunchKernelGGL(prep_kernel, dim3(160), dim3(256), 0, stream,
                     W_ih, W_hh, b_ih, b_hh, Wr, biasp);
  hipLaunchKernelGGL(lstm_kernel, dim3(NBLK), dim3(NTHR), 0, stream,
                     x, Wr, biasp, fcW, fcb, out);
}